// Round 9
// baseline (187.049 us; speedup 1.0000x reference)
//
#include <hip/hip_runtime.h>

#define SP    65536      // 16*64*64 spatial voxels
#define DD    16
#define HH    64
#define WW    64
#define CIN   64
#define COUT  64

#define XPAD  68         // x-tile LDS row pitch (16B-aligned rows, stride-1 lane reads)

// ws layout (fp32): q [64][SP] | k [64][SP] | v [64][SP]   (48 MB total)

// proj v3: wave-uniform channel assignment. Block = 64 positions, all 64
// output channels, all 3 matrices. Wave w handles channels [16w,16w+16);
// lane = position. Weight addresses are scalar (readfirstlane) -> s_load
// on the SMEM pipe; x column lives in VGPRs (read once from LDS with
// conflict-free stride-1 ds_read_b32). Inner loop is pure FMA -> VALU-bound
// (round-8 version moved 2 B of LDS per lane-FMA; LDS is one 128 B/cy unit
// per CU shared by 4 SIMDs -> was 2x LDS-oversubscribed).
__global__ __launch_bounds__(256) void proj(const float* __restrict__ x,
                                            const float* __restrict__ wq,
                                            const float* __restrict__ wk,
                                            const float* __restrict__ wv,
                                            float* __restrict__ q,
                                            float* __restrict__ k,
                                            float* __restrict__ v) {
    __shared__ float xl[CIN][XPAD];    // [c][p], 17.4 KB

    const int t  = threadIdx.x;
    const int p0 = blockIdx.x * 64;

    // stage x tile: 64c x 64p = 1024 float4, coalesced
#pragma unroll
    for (int i = 0; i < 4; ++i) {
        const int f = t + 256 * i;
        const int c = f >> 4, j = f & 15;
        *(float4*)(&xl[c][j * 4]) = *(const float4*)(x + c * SP + p0 + j * 4);
    }
    __syncthreads();

    const int lane  = t & 63;
    const int wvid  = __builtin_amdgcn_readfirstlane(t >> 6);   // 0..3, scalar
    const int obase = wvid * 16;

    // x column -> VGPRs (64 regs); stride-1 across lanes, 2-way bank = free
    float xv[CIN];
#pragma unroll
    for (int c = 0; c < CIN; ++c)
        xv[c] = xl[c][lane];

#pragma unroll 1
    for (int m = 0; m < 3; ++m) {
        const float* __restrict__ wsel = (m == 0) ? wq : (m == 1) ? wk : wv;
        float* __restrict__       osel = (m == 0) ? q  : (m == 1) ? k  : v;

#pragma unroll 1
        for (int oo = 0; oo < 16; ++oo) {
            const int o = obase + oo;                 // scalar
            const float* __restrict__ wrow = wsel + o * CIN;
            float acc = 0.f;
#pragma unroll
            for (int c4 = 0; c4 < CIN / 4; ++c4) {
                const float4 w4 = *(const float4*)(wrow + c4 * 4);  // s_load (uniform addr)
                acc = fmaf(w4.x, xv[4 * c4 + 0], acc);
                acc = fmaf(w4.y, xv[4 * c4 + 1], acc);
                acc = fmaf(w4.z, xv[4 * c4 + 2], acc);
                acc = fmaf(w4.w, xv[4 * c4 + 3], acc);
            }
            osel[o * SP + p0 + lane] = acc;
        }
    }
}

// DPP cross-lane shifts within 16-lane rows; bound_ctrl=1 -> out-of-row
// source reads 0, matching the w-boundary zero-pad (wg==0/15 are DPP row
// boundaries).
__device__ __forceinline__ float dpp_shr1(float x) {   // lane i <- lane i-1
    return __int_as_float(__builtin_amdgcn_mov_dpp(__float_as_int(x), 0x111, 0xf, 0xf, true));
}
__device__ __forceinline__ float dpp_shl1(float x) {   // lane i <- lane i+1
    return __int_as_float(__builtin_amdgcn_mov_dpp(__float_as_int(x), 0x101, 0xf, 0xf, true));
}

// axis-specialized compute over the staged LDS tiles
template<int AXIS>
__device__ __forceinline__ void attn_compute(const float* __restrict__ kt,
                                             const float* __restrict__ vt,
                                             const float (&qs)[4][4],
                                             float r0, float r1, float r2,
                                             int wg, int h, int dg,
                                             float (&s)[4][4], float (&a)[4][4]) {
#pragma unroll 1
    for (int m = 0; m < 6; ++m) {          // halo dp = dg*4 + m
#pragma unroll 1
        for (int kh = 0; kh < 3; ++kh) {
            const int row = (dg * 4 + m) * 10 + (h + kh);
            const float4 km = *(const float4*)(kt + row * 64 + wg * 4);
            const float4 vm = *(const float4*)(vt + row * 64 + wg * 4);
            const float kl = dpp_shr1(km.w), kr = dpp_shl1(km.x);
            const float vl = dpp_shr1(vm.w), vr = dpp_shl1(vm.x);
            const float krow[6] = { kl, km.x, km.y, km.z, km.w, kr };
            const float vrow[6] = { vl, vm.x, vm.y, vm.z, vm.w, vr };

            const float rkh = (kh == 0) ? r0 : (kh == 1) ? r1 : r2;

#pragma unroll
            for (int di = 0; di < 4; ++di) {
                const int kd = m - di;
                if ((unsigned)kd < 3u) {
                    const float rdd = (kd == 0) ? r0 : (kd == 1) ? r1 : r2;
                    const float rr  = (AXIS == 0) ? rdd : (AXIS == 1) ? rkh : 0.f;
#pragma unroll
                    for (int wi = 0; wi < 4; ++wi) {
                        const float qv = qs[di][wi];
#pragma unroll
                        for (int kw = 0; kw < 3; ++kw) {
                            const float rc = (AXIS == 2)
                                           ? ((kw == 0) ? r0 : (kw == 1) ? r1 : r2)
                                           : rr;
                            const float e = __expf(qv * (krow[wi + kw] + rc));
                            s[di][wi] += e;
                            a[di][wi] = fmaf(e, vrow[wi + kw], a[di][wi]);
                        }
                    }
                }
            }
        }
    }
}

// attn, LDS-tiled, single launch: block = (dtile, htile, o) covering
// 8d x 8h x 64w outputs of one channel. Stage k,v halo tiles [10][10][64],
// one barrier, all-LDS compute (thread = 4d x 4w), axis picked by a
// block-uniform branch. Single-pass softmax (logits bounded); OOB: k=0+rel
// stays in softmax, v=0.
__global__ __launch_bounds__(256) void attn(const float* __restrict__ kbuf,
                                            const float* __restrict__ vbuf,
                                            const float* __restrict__ qbuf,
                                            const float* __restrict__ rel_d,
                                            const float* __restrict__ rel_h,
                                            const float* __restrict__ rel_w,
                                            float* __restrict__ out) {
    __shared__ float kt[100 * 64];   // [dp][hp][w] halo'd, 25.6 KB
    __shared__ float vt[100 * 64];

    const int dt = blockIdx.x;       // 0..1
    const int ht = blockIdx.y;       // 0..7
    const int o  = blockIdx.z;       // 0..63

    const int d0 = dt * 8;
    const int h0 = ht * 8;
    const int t  = threadIdx.x;

    const float* __restrict__ kc = kbuf + o * SP;
    const float* __restrict__ vc = vbuf + o * SP;

    // ---- stage k,v halo tiles: 2 * 100 rows * 16 float4 ----
#pragma unroll
    for (int i = 0; i < 13; ++i) {
        const int idx = t + 256 * i;
        if (idx < 3200) {
            const bool isv = idx >= 1600;
            const int rem  = isv ? idx - 1600 : idx;
            const int row  = rem >> 4;
            const int j    = rem & 15;
            const int dp   = row / 10;
            const int hp   = row - dp * 10;
            const int dpg  = d0 - 1 + dp;
            const int hpg  = h0 - 1 + hp;
            float4 val = make_float4(0.f, 0.f, 0.f, 0.f);
            if ((unsigned)dpg < (unsigned)DD && (unsigned)hpg < (unsigned)HH) {
                const float* src = (isv ? vc : kc) + (dpg * HH + hpg) * WW + j * 4;
                val = *(const float4*)src;
            }
            *(float4*)((isv ? vt : kt) + row * 64 + j * 4) = val;
        }
    }

    const int wg = t & 15;
    const int h  = (t >> 4) & 7;
    const int dg = t >> 7;

    float qs[4][4];
#pragma unroll
    for (int di = 0; di < 4; ++di) {
        const int dabs = d0 + dg * 4 + di;
        const float4 q4 = *(const float4*)(qbuf + o * SP + (dabs * HH + (h0 + h)) * WW + wg * 4);
        qs[di][0] = q4.x; qs[di][1] = q4.y; qs[di][2] = q4.z; qs[di][3] = q4.w;
    }

    __syncthreads();

    float s[4][4] = {};
    float a[4][4] = {};

    if (o < 21) {
        attn_compute<0>(kt, vt, qs, rel_d[o * 3 + 0], rel_d[o * 3 + 1], rel_d[o * 3 + 2],
                        wg, h, dg, s, a);
    } else if (o < 42) {
        const int b = o - 21;
        attn_compute<1>(kt, vt, qs, rel_h[b * 3 + 0], rel_h[b * 3 + 1], rel_h[b * 3 + 2],
                        wg, h, dg, s, a);
    } else {
        const int b = o - 42;
        attn_compute<2>(kt, vt, qs, rel_w[b * 3 + 0], rel_w[b * 3 + 1], rel_w[b * 3 + 2],
                        wg, h, dg, s, a);
    }

#pragma unroll
    for (int di = 0; di < 4; ++di) {
        const int dabs = d0 + dg * 4 + di;
        float4 ov;
        ov.x = a[di][0] * __builtin_amdgcn_rcpf(s[di][0]);
        ov.y = a[di][1] * __builtin_amdgcn_rcpf(s[di][1]);
        ov.z = a[di][2] * __builtin_amdgcn_rcpf(s[di][2]);
        ov.w = a[di][3] * __builtin_amdgcn_rcpf(s[di][3]);
        *(float4*)(out + o * SP + (dabs * HH + (h0 + h)) * WW + wg * 4) = ov;
    }
}

extern "C" void kernel_launch(void* const* d_in, const int* in_sizes, int n_in,
                              void* d_out, int out_size, void* d_ws, size_t ws_size,
                              hipStream_t stream) {
    const float* x     = (const float*)d_in[0];
    const float* w_q   = (const float*)d_in[1];
    const float* w_k   = (const float*)d_in[2];
    const float* w_v   = (const float*)d_in[3];
    const float* rel_d = (const float*)d_in[4];
    const float* rel_h = (const float*)d_in[5];
    const float* rel_w = (const float*)d_in[6];
    float* out = (float*)d_out;

    float* ws = (float*)d_ws;
    float* q  = ws;
    float* k  = ws + (size_t)COUT * SP;
    float* v  = ws + 2 * (size_t)COUT * SP;

    proj<<<SP / 64, 256, 0, stream>>>(x, w_q, w_k, w_v, q, k, v);
    attn<<<dim3(2, 8, 64), 256, 0, stream>>>(k, v, q, rel_d, rel_h, rel_w, out);
}

// Round 11
// 131.076 us; speedup vs baseline: 1.4270x; 1.4270x over previous
//
#include <hip/hip_runtime.h>

#define SP    65536      // 16*64*64 spatial voxels
#define DD    16
#define HH    64
#define WW    64
#define CIN   64
#define COUT  64

#define XP    132        // proj x-tile pitch (floats): 128+4, 16B-aligned rows
#define WP    68         // proj w-tile pitch

// ws layout (fp32): q [64][SP] | k [64][SP] | v [64][SP]   (48 MB)
// NOTE round-10: bf16 k fails accuracy (k feeds exp(); Dlogit = q*Dk ~ 0.06
// -> absmax 0.156 > 0.131). Intermediates stay fp32.

// proj: LDS GEMM, one matrix per block (grid 512 x 3), single barrier.
// Block = 128 positions x 64 channels; thread tile 8o x 4p = 1.5 B of LDS
// per lane-FMA (round-8's 4o x 4p moved 2.0 B/FMA; LDS is one 128 B/cy unit
// shared by 4 SIMDs at ~128 FMA/cy -> was the limiter).
// round-9 lesson: weights must come from LDS, not scalar s_load (SMEM
// latency exposed per o-iteration, 87 us).
__global__ __launch_bounds__(256) void proj(const float* __restrict__ x,
                                            const float* __restrict__ wq,
                                            const float* __restrict__ wk,
                                            const float* __restrict__ wv,
                                            float* __restrict__ q,
                                            float* __restrict__ k,
                                            float* __restrict__ v) {
    __shared__ float xl[CIN][XP];     // [c][p] 33.8 KB
    __shared__ float wl[COUT][WP];    // [o][c] 17.4 KB

    const int t  = threadIdx.x;
    const int p0 = blockIdx.x * 128;
    const int m  = blockIdx.y;

    const float* __restrict__ wsel = (m == 0) ? wq : (m == 1) ? wk : wv;
    float* __restrict__       osel = (m == 0) ? q  : (m == 1) ? k  : v;

    // stage x tile: 64c x 128p = 2048 float4 (8/thread), coalesced per c-row
#pragma unroll
    for (int i = 0; i < 8; ++i) {
        const int f = t + 256 * i;
        const int c = f >> 5, j = f & 31;
        *(float4*)(&xl[c][j * 4]) = *(const float4*)(x + c * SP + p0 + j * 4);
    }
    // stage weight matrix: 1024 float4 (4/thread)
#pragma unroll
    for (int i = 0; i < 4; ++i) {
        const int f = t + 256 * i;
        const int o = f >> 4, j = f & 15;
        *(float4*)(&wl[o][j * 4]) = *(const float4*)(wsel + o * CIN + j * 4);
    }
    __syncthreads();

    const int og    = t >> 5;        // 0..7
    const int pg    = t & 31;        // 0..31
    const int obase = og * 8;
    const int pbase = pg * 4;

    float acc[8][4] = {};
#pragma unroll 2
    for (int c4 = 0; c4 < CIN / 4; ++c4) {
        float4 w4[8], x4[4];
#pragma unroll
        for (int i = 0; i < 8; ++i)
            w4[i] = *(const float4*)(&wl[obase + i][c4 * 4]);
#pragma unroll
        for (int cc = 0; cc < 4; ++cc)
            x4[cc] = *(const float4*)(&xl[c4 * 4 + cc][pbase]);
#pragma unroll
        for (int i = 0; i < 8; ++i) {
            const float* wf = (const float*)&w4[i];
#pragma unroll
            for (int cc = 0; cc < 4; ++cc) {
                const float* xf = (const float*)&x4[cc];
                const float wv_ = wf[cc];
                acc[i][0] = fmaf(wv_, xf[0], acc[i][0]);
                acc[i][1] = fmaf(wv_, xf[1], acc[i][1]);
                acc[i][2] = fmaf(wv_, xf[2], acc[i][2]);
                acc[i][3] = fmaf(wv_, xf[3], acc[i][3]);
            }
        }
    }

#pragma unroll
    for (int i = 0; i < 8; ++i)
        *(float4*)(osel + (obase + i) * SP + p0 + pbase) =
            make_float4(acc[i][0], acc[i][1], acc[i][2], acc[i][3]);
}

// DPP shifts within 16-lane rows; bound_ctrl=1 -> out-of-row reads 0 =
// exactly the w-boundary zero-pad (wg==0/15 are DPP row boundaries).
__device__ __forceinline__ float dpp_shr1(float x) {   // lane i <- lane i-1
    return __int_as_float(__builtin_amdgcn_mov_dpp(__float_as_int(x), 0x111, 0xf, 0xf, true));
}
__device__ __forceinline__ float dpp_shl1(float x) {   // lane i <- lane i+1
    return __int_as_float(__builtin_amdgcn_mov_dpp(__float_as_int(x), 0x101, 0xf, 0xf, true));
}

// axis-specialized compute over the staged LDS tiles
template<int AXIS>
__device__ __forceinline__ void attn_compute(const float* __restrict__ kt,
                                             const float* __restrict__ vt,
                                             const float (&qs)[4][4],
                                             float r0, float r1, float r2,
                                             int wg, int h, int dg,
                                             float (&s)[4][4], float (&a)[4][4]) {
#pragma unroll 1
    for (int m = 0; m < 6; ++m) {          // halo dp = dg*4 + m
#pragma unroll 1
        for (int kh = 0; kh < 3; ++kh) {
            const int row = (dg * 4 + m) * 10 + (h + kh);
            const float4 km = *(const float4*)(kt + row * 64 + wg * 4);
            const float4 vm = *(const float4*)(vt + row * 64 + wg * 4);
            const float kl = dpp_shr1(km.w), kr = dpp_shl1(km.x);
            const float vl = dpp_shr1(vm.w), vr = dpp_shl1(vm.x);
            const float krow[6] = { kl, km.x, km.y, km.z, km.w, kr };
            const float vrow[6] = { vl, vm.x, vm.y, vm.z, vm.w, vr };

            const float rkh = (kh == 0) ? r0 : (kh == 1) ? r1 : r2;

#pragma unroll
            for (int di = 0; di < 4; ++di) {
                const int kd = m - di;
                if ((unsigned)kd < 3u) {
                    const float rdd = (kd == 0) ? r0 : (kd == 1) ? r1 : r2;
                    const float rr  = (AXIS == 0) ? rdd : (AXIS == 1) ? rkh : 0.f;
#pragma unroll
                    for (int wi = 0; wi < 4; ++wi) {
                        const float qv = qs[di][wi];
#pragma unroll
                        for (int kw = 0; kw < 3; ++kw) {
                            const float rc = (AXIS == 2)
                                           ? ((kw == 0) ? r0 : (kw == 1) ? r1 : r2)
                                           : rr;
                            const float e = __expf(qv * (krow[wi + kw] + rc));
                            s[di][wi] += e;
                            a[di][wi] = fmaf(e, vrow[wi + kw], a[di][wi]);
                        }
                    }
                }
            }
        }
    }
}

// attn, LDS-tiled, single launch: block = (dtile, htile, o) covering
// 8d x 8h x 64w outputs of one channel. Stage k,v halo tiles [10][10][64],
// one barrier, all-LDS compute (thread = 4d x 4w), axis picked by a
// block-uniform branch. Single-pass softmax (logits bounded); OOB: k=0+rel
// stays in softmax, v=0.
__global__ __launch_bounds__(256) void attn(const float* __restrict__ kbuf,
                                            const float* __restrict__ vbuf,
                                            const float* __restrict__ qbuf,
                                            const float* __restrict__ rel_d,
                                            const float* __restrict__ rel_h,
                                            const float* __restrict__ rel_w,
                                            float* __restrict__ out) {
    __shared__ float kt[100 * 64];   // [dp][hp][w] halo'd, 25.6 KB
    __shared__ float vt[100 * 64];

    const int dt = blockIdx.x;       // 0..1
    const int ht = blockIdx.y;       // 0..7
    const int o  = blockIdx.z;       // 0..63

    const int d0 = dt * 8;
    const int h0 = ht * 8;
    const int t  = threadIdx.x;

    const float* __restrict__ kc = kbuf + o * SP;
    const float* __restrict__ vc = vbuf + o * SP;

    // stage k,v halo tiles: 2 * 100 rows * 16 float4
#pragma unroll
    for (int i = 0; i < 13; ++i) {
        const int idx = t + 256 * i;
        if (idx < 3200) {
            const bool isv = idx >= 1600;
            const int rem  = isv ? idx - 1600 : idx;
            const int row  = rem >> 4;
            const int j    = rem & 15;
            const int dp   = row / 10;
            const int hp   = row - dp * 10;
            const int dpg  = d0 - 1 + dp;
            const int hpg  = h0 - 1 + hp;
            float4 val = make_float4(0.f, 0.f, 0.f, 0.f);
            if ((unsigned)dpg < (unsigned)DD && (unsigned)hpg < (unsigned)HH) {
                const float* src = (isv ? vc : kc) + (dpg * HH + hpg) * WW + j * 4;
                val = *(const float4*)src;
            }
            *(float4*)((isv ? vt : kt) + row * 64 + j * 4) = val;
        }
    }

    const int wg = t & 15;
    const int h  = (t >> 4) & 7;
    const int dg = t >> 7;

    float qs[4][4];
#pragma unroll
    for (int di = 0; di < 4; ++di) {
        const int dabs = d0 + dg * 4 + di;
        const float4 q4 = *(const float4*)(qbuf + o * SP + (dabs * HH + (h0 + h)) * WW + wg * 4);
        qs[di][0] = q4.x; qs[di][1] = q4.y; qs[di][2] = q4.z; qs[di][3] = q4.w;
    }

    __syncthreads();

    float s[4][4] = {};
    float a[4][4] = {};

    if (o < 21) {
        attn_compute<0>(kt, vt, qs, rel_d[o * 3 + 0], rel_d[o * 3 + 1], rel_d[o * 3 + 2],
                        wg, h, dg, s, a);
    } else if (o < 42) {
        const int b = o - 21;
        attn_compute<1>(kt, vt, qs, rel_h[b * 3 + 0], rel_h[b * 3 + 1], rel_h[b * 3 + 2],
                        wg, h, dg, s, a);
    } else {
        const int b = o - 42;
        attn_compute<2>(kt, vt, qs, rel_w[b * 3 + 0], rel_w[b * 3 + 1], rel_w[b * 3 + 2],
                        wg, h, dg, s, a);
    }

#pragma unroll
    for (int di = 0; di < 4; ++di) {
        const int dabs = d0 + dg * 4 + di;
        float4 ov;
        ov.x = a[di][0] * __builtin_amdgcn_rcpf(s[di][0]);
        ov.y = a[di][1] * __builtin_amdgcn_rcpf(s[di][1]);
        ov.z = a[di][2] * __builtin_amdgcn_rcpf(s[di][2]);
        ov.w = a[di][3] * __builtin_amdgcn_rcpf(s[di][3]);
        *(float4*)(out + o * SP + (dabs * HH + (h0 + h)) * WW + wg * 4) = ov;
    }
}

extern "C" void kernel_launch(void* const* d_in, const int* in_sizes, int n_in,
                              void* d_out, int out_size, void* d_ws, size_t ws_size,
                              hipStream_t stream) {
    const float* x     = (const float*)d_in[0];
    const float* w_q   = (const float*)d_in[1];
    const float* w_k   = (const float*)d_in[2];
    const float* w_v   = (const float*)d_in[3];
    const float* rel_d = (const float*)d_in[4];
    const float* rel_h = (const float*)d_in[5];
    const float* rel_w = (const float*)d_in[6];
    float* out = (float*)d_out;

    float* ws = (float*)d_ws;
    float* q  = ws;
    float* k  = ws + (size_t)COUT * SP;
    float* v  = ws + 2 * (size_t)COUT * SP;

    proj<<<dim3(SP / 128, 3), 256, 0, stream>>>(x, w_q, w_k, w_v, q, k, v);
    attn<<<dim3(2, 8, 64), 256, 0, stream>>>(k, v, q, rel_d, rel_h, rel_w, out);
}

// Round 12
// 125.693 us; speedup vs baseline: 1.4881x; 1.0428x over previous
//
#include <hip/hip_runtime.h>

#define SP    65536      // 16*64*64 spatial voxels
#define DD    16
#define HH    64
#define WW    64
#define CIN   64
#define COUT  64

#define XP    132        // proj x-tile pitch (floats)
#define WP    68         // proj w-tile pitch

#define LOG2E 1.44269504f

// ws layout (fp32): q [64][SP] | k [64][SP] | v [64][SP]   (48 MB)
// round-10 lesson: bf16 k fails accuracy (k feeds exp; Dlogit=q*Dk~0.06 ->
// absmax 0.156 > 0.131). Intermediates stay fp32.
// round-9 lesson: proj weights must come from LDS, not scalar s_load.

__global__ __launch_bounds__(256) void proj(const float* __restrict__ x,
                                            const float* __restrict__ wq,
                                            const float* __restrict__ wk,
                                            const float* __restrict__ wv,
                                            float* __restrict__ q,
                                            float* __restrict__ k,
                                            float* __restrict__ v) {
    __shared__ float xl[CIN][XP];     // [c][p] 33.8 KB
    __shared__ float wl[COUT][WP];    // [o][c] 17.4 KB

    const int t  = threadIdx.x;
    const int p0 = blockIdx.x * 128;
    const int m  = blockIdx.y;

    const float* __restrict__ wsel = (m == 0) ? wq : (m == 1) ? wk : wv;
    float* __restrict__       osel = (m == 0) ? q  : (m == 1) ? k  : v;

#pragma unroll
    for (int i = 0; i < 8; ++i) {
        const int f = t + 256 * i;
        const int c = f >> 5, j = f & 31;
        *(float4*)(&xl[c][j * 4]) = *(const float4*)(x + c * SP + p0 + j * 4);
    }
#pragma unroll
    for (int i = 0; i < 4; ++i) {
        const int f = t + 256 * i;
        const int o = f >> 4, j = f & 15;
        *(float4*)(&wl[o][j * 4]) = *(const float4*)(wsel + o * CIN + j * 4);
    }
    __syncthreads();

    const int og    = t >> 5;        // 0..7
    const int pg    = t & 31;        // 0..31
    const int obase = og * 8;
    const int pbase = pg * 4;

    float acc[8][4] = {};
#pragma unroll 2
    for (int c4 = 0; c4 < CIN / 4; ++c4) {
        float4 w4[8], x4[4];
#pragma unroll
        for (int i = 0; i < 8; ++i)
            w4[i] = *(const float4*)(&wl[obase + i][c4 * 4]);
#pragma unroll
        for (int cc = 0; cc < 4; ++cc)
            x4[cc] = *(const float4*)(&xl[c4 * 4 + cc][pbase]);
#pragma unroll
        for (int i = 0; i < 8; ++i) {
            const float* wf = (const float*)&w4[i];
#pragma unroll
            for (int cc = 0; cc < 4; ++cc) {
                const float* xf = (const float*)&x4[cc];
                const float wv_ = wf[cc];
                acc[i][0] = fmaf(wv_, xf[0], acc[i][0]);
                acc[i][1] = fmaf(wv_, xf[1], acc[i][1]);
                acc[i][2] = fmaf(wv_, xf[2], acc[i][2]);
                acc[i][3] = fmaf(wv_, xf[3], acc[i][3]);
            }
        }
    }

#pragma unroll
    for (int i = 0; i < 8; ++i)
        *(float4*)(osel + (obase + i) * SP + p0 + pbase) =
            make_float4(acc[i][0], acc[i][1], acc[i][2], acc[i][3]);
}

// DPP shifts within 16-lane rows; bound_ctrl=1 -> out-of-row reads 0 =
// exactly the w-boundary zero-pad (wg==0/15 are DPP row boundaries).
__device__ __forceinline__ float dpp_shr1(float x) {   // lane i <- lane i-1
    return __int_as_float(__builtin_amdgcn_mov_dpp(__float_as_int(x), 0x111, 0xf, 0xf, true));
}
__device__ __forceinline__ float dpp_shl1(float x) {   // lane i <- lane i+1
    return __int_as_float(__builtin_amdgcn_mov_dpp(__float_as_int(x), 0x101, 0xf, 0xf, true));
}

// attn v3 compute: fully unrolled halo walk, compile-time row indices and
// kd guards -> compiler hoists/interleaves all ds_read_b128 (the previous
// unroll-1 loops exposed ~120cy LDS latency per row at 3 waves/SIMD).
// e = exp2(ql*(k+r)) with ql = q*log2e.
template<int AXIS>
__device__ __forceinline__ void attn_tile(const float* __restrict__ kt,
                                          const float* __restrict__ vt,
                                          const float (&ql)[2][4],
                                          float r0, float r1, float r2,
                                          int wg, int h, int dg,
                                          float (&s)[2][4], float (&a)[2][4]) {
#pragma unroll
    for (int nl = 0; nl < 4; ++nl) {             // local halo d-row
#pragma unroll
        for (int kh = 0; kh < 3; ++kh) {
            const int off = ((dg * 2 + nl) * 10 + h + kh) * 64 + wg * 4;
            const float4 km = *(const float4*)(kt + off);
            const float4 vm = *(const float4*)(vt + off);
            const float kl = dpp_shr1(km.w), kr = dpp_shl1(km.x);
            const float vl = dpp_shr1(vm.w), vr = dpp_shl1(vm.x);
            const float krow[6] = { kl, km.x, km.y, km.z, km.w, kr };
            const float vrow[6] = { vl, vm.x, vm.y, vm.z, vm.w, vr };

            const float rkh = (kh == 0) ? r0 : (kh == 1) ? r1 : r2;

#pragma unroll
            for (int di = 0; di < 2; ++di) {
                const int kd = nl - di;          // compile-time
                if (kd >= 0 && kd < 3) {
                    const float rdd = (kd == 0) ? r0 : (kd == 1) ? r1 : r2;
                    const float rr  = (AXIS == 0) ? rdd : (AXIS == 1) ? rkh : 0.f;
#pragma unroll
                    for (int wi = 0; wi < 4; ++wi) {
                        const float qv = ql[di][wi];
#pragma unroll
                        for (int kw = 0; kw < 3; ++kw) {
                            const float rc = (AXIS == 2)
                                           ? ((kw == 0) ? r0 : (kw == 1) ? r1 : r2)
                                           : rr;
                            const float e = __builtin_amdgcn_exp2f(qv * (krow[wi + kw] + rc));
                            s[di][wi] += e;
                            a[di][wi] = fmaf(e, vrow[wi + kw], a[di][wi]);
                        }
                    }
                }
            }
        }
    }
}

// attn v3: block = (dtile4, htile8, o) -> 4d x 8h x 64w outputs of one
// channel. LDS halo tiles [6][10][64] k+v = 30 KB -> 5 blocks/CU (was 3).
// Thread = 2d x 4w. Single-pass softmax; OOB: k=0+rel in softmax, v=0.
__global__ __launch_bounds__(256) void attn(const float* __restrict__ kbuf,
                                            const float* __restrict__ vbuf,
                                            const float* __restrict__ qbuf,
                                            const float* __restrict__ rel_d,
                                            const float* __restrict__ rel_h,
                                            const float* __restrict__ rel_w,
                                            float* __restrict__ out) {
    __shared__ float kt[60 * 64];    // [nn][hp][w], 15 KB
    __shared__ float vt[60 * 64];

    const int dt = blockIdx.x;       // 0..3
    const int ht = blockIdx.y;       // 0..7
    const int o  = blockIdx.z;       // 0..63

    const int d0 = dt * 4;
    const int h0 = ht * 8;
    const int t  = threadIdx.x;

    const float* __restrict__ kc = kbuf + o * SP;
    const float* __restrict__ vc = vbuf + o * SP;

    // stage k,v halo tiles: 2 * 60 rows * 16 float4 = 1920 float4
#pragma unroll
    for (int i = 0; i < 8; ++i) {
        const int idx = t + 256 * i;
        if (idx < 1920) {
            const bool isv = idx >= 960;
            const int rem  = isv ? idx - 960 : idx;
            const int row  = rem >> 4;         // 0..59
            const int j    = rem & 15;
            const int nn   = row / 10;
            const int hp   = row - nn * 10;
            const int dpg  = d0 - 1 + nn;
            const int hpg  = h0 - 1 + hp;
            float4 val = make_float4(0.f, 0.f, 0.f, 0.f);
            if ((unsigned)dpg < (unsigned)DD && (unsigned)hpg < (unsigned)HH) {
                const float* src = (isv ? vc : kc) + (dpg * HH + hpg) * WW + j * 4;
                val = *(const float4*)src;
            }
            *(float4*)((isv ? vt : kt) + row * 64 + j * 4) = val;
        }
    }

    const int wg = t & 15;           // 4w each
    const int h  = (t >> 4) & 7;
    const int dg = t >> 7;           // 0/1: d-pair

    float ql[2][4];
#pragma unroll
    for (int di = 0; di < 2; ++di) {
        const int dabs = d0 + dg * 2 + di;
        const float4 q4 = *(const float4*)(qbuf + o * SP + (dabs * HH + (h0 + h)) * WW + wg * 4);
        ql[di][0] = q4.x * LOG2E; ql[di][1] = q4.y * LOG2E;
        ql[di][2] = q4.z * LOG2E; ql[di][3] = q4.w * LOG2E;
    }

    __syncthreads();

    float s[2][4] = {};
    float a[2][4] = {};

    if (o < 21) {
        attn_tile<0>(kt, vt, ql, rel_d[o * 3 + 0], rel_d[o * 3 + 1], rel_d[o * 3 + 2],
                     wg, h, dg, s, a);
    } else if (o < 42) {
        const int b = o - 21;
        attn_tile<1>(kt, vt, ql, rel_h[b * 3 + 0], rel_h[b * 3 + 1], rel_h[b * 3 + 2],
                     wg, h, dg, s, a);
    } else {
        const int b = o - 42;
        attn_tile<2>(kt, vt, ql, rel_w[b * 3 + 0], rel_w[b * 3 + 1], rel_w[b * 3 + 2],
                     wg, h, dg, s, a);
    }

#pragma unroll
    for (int di = 0; di < 2; ++di) {
        const int dabs = d0 + dg * 2 + di;
        float4 ov;
        ov.x = a[di][0] * __builtin_amdgcn_rcpf(s[di][0]);
        ov.y = a[di][1] * __builtin_amdgcn_rcpf(s[di][1]);
        ov.z = a[di][2] * __builtin_amdgcn_rcpf(s[di][2]);
        ov.w = a[di][3] * __builtin_amdgcn_rcpf(s[di][3]);
        *(float4*)(out + o * SP + (dabs * HH + (h0 + h)) * WW + wg * 4) = ov;
    }
}

extern "C" void kernel_launch(void* const* d_in, const int* in_sizes, int n_in,
                              void* d_out, int out_size, void* d_ws, size_t ws_size,
                              hipStream_t stream) {
    const float* x     = (const float*)d_in[0];
    const float* w_q   = (const float*)d_in[1];
    const float* w_k   = (const float*)d_in[2];
    const float* w_v   = (const float*)d_in[3];
    const float* rel_d = (const float*)d_in[4];
    const float* rel_h = (const float*)d_in[5];
    const float* rel_w = (const float*)d_in[6];
    float* out = (float*)d_out;

    float* ws = (float*)d_ws;
    float* q  = ws;
    float* k  = ws + (size_t)COUT * SP;
    float* v  = ws + 2 * (size_t)COUT * SP;

    proj<<<dim3(SP / 128, 3), 256, 0, stream>>>(x, w_q, w_k, w_v, q, k, v);
    attn<<<dim3(4, 8, 64), 256, 0, stream>>>(k, v, q, rel_d, rel_h, rel_w, out);
}